// Round 15
// baseline (127.477 us; speedup 1.0000x reference)
//
#include <hip/hip_runtime.h>
#include <hip/hip_bf16.h>

typedef __attribute__((ext_vector_type(8))) __bf16 bfrag;
typedef __attribute__((ext_vector_type(4))) float f32x4;
typedef __attribute__((ext_vector_type(16))) float f32x16;
typedef __attribute__((ext_vector_type(8))) unsigned short u16x8;
typedef __attribute__((ext_vector_type(4))) unsigned short u16x4;
typedef __attribute__((ext_vector_type(4))) unsigned int u32x4;

#define SEQ 2048
#define NH 16
#define HD 64
#define DMODEL 1024
#define MTOT 4096
// 1/sqrt(64) * log2(e): folded into Q so softmax uses exp2 directly
#define QSCALE 0.18033688011112042f

static __device__ __forceinline__ unsigned short f2bf(float f) {
  unsigned int u = __builtin_bit_cast(unsigned int, f);
  u += 0x7FFFu + ((u >> 16) & 1u);
  return (unsigned short)(u >> 16);
}

static __device__ __forceinline__ unsigned cvt_pk_bf16(float lo, float hi) {
  unsigned r;
  asm("v_cvt_pk_bf16_f32 %0, %1, %2" : "=v"(r) : "v"(lo), "v"(hi));
  return r;
}

static __device__ __forceinline__ float rsum16(const f32x16 v) {
  float a0 = v[0] + v[1], a1 = v[2] + v[3], a2 = v[4] + v[5], a3 = v[6] + v[7];
  float a4 = v[8] + v[9], a5 = v[10] + v[11], a6 = v[12] + v[13], a7 = v[14] + v[15];
  float b0 = a0 + a1, b1 = a2 + a3, b2 = a4 + a5, b3 = a6 + a7;
  return (b0 + b1) + (b2 + b3);
}

// ---------------- f32 -> bf16 convert: all three tensors in ONE launch -------------
#define XG 524288   // 4096*1024/8
#define WQG 393216  // 3*1024*1024/8
#define WOG 131072  // 1024*1024/8
__global__ __launch_bounds__(256) void cvt_all_kernel(const float* __restrict__ x,
                                                      const float* __restrict__ wq,
                                                      const float* __restrict__ wo,
                                                      unsigned short* __restrict__ out) {
  int i = blockIdx.x * 256 + threadIdx.x;
  if (i >= XG + WQG + WOG) return;
  const float4* p;
  if (i < XG) p = reinterpret_cast<const float4*>(x) + (size_t)i * 2;
  else if (i < XG + WQG) p = reinterpret_cast<const float4*>(wq) + (size_t)(i - XG) * 2;
  else p = reinterpret_cast<const float4*>(wo) + (size_t)(i - XG - WQG) * 2;
  float4 a = p[0], b = p[1];
  u16x8 o;
  o[0] = f2bf(a.x); o[1] = f2bf(a.y); o[2] = f2bf(a.z); o[3] = f2bf(a.w);
  o[4] = f2bf(b.x); o[5] = f2bf(b.y); o[6] = f2bf(b.z); o[7] = f2bf(b.w);
  *(reinterpret_cast<u16x8*>(out) + i) = o;
}

#define GLDS(gp, lp)                                                       \
  __builtin_amdgcn_global_load_lds(                                        \
      (const __attribute__((address_space(1))) void*)(gp),                 \
      (__attribute__((address_space(3))) void*)(lp), 16, 0, 0)

// ---------------- GEMM C = A * B^T + bias, 128x128 tile, BK=64, ring-2 ----------------
// r15: K-step 32 -> 64. Barriers halve (32 -> 16); 32 MFMA + 16 ds_read_b128 per
// phase amortize the barrier drain (m233: drain was ~20% at BK=32). LDS = 2 bufs x
// (16KB A + 16KB B) = 64KB -> still 2 blocks/CU. Staging = attn's proven 8-issue
// pattern, 16B-chunk XOR swizzle keyed by row&7, inverse on global src (rule #21).
// XCD-chunked remap kept from r14.
template <int EPI>
__global__ __launch_bounds__(256) void gemm_bt_kernel(
    const unsigned short* __restrict__ A, const unsigned short* __restrict__ B,
    const float* __restrict__ bias, unsigned short* __restrict__ q_out,
    unsigned short* __restrict__ k_out, unsigned short* __restrict__ v_out,
    float* __restrict__ f_out, int M, int N, int K) {
  __shared__ __align__(16) unsigned short As[2][8192];  // [128 rows][64 k]
  __shared__ __align__(16) unsigned short Bs[2][8192];
  const int t = threadIdx.x;
  const int l = t & 63, w = t >> 6;
  const int total = gridDim.x * gridDim.y;
  const int lid0 = blockIdx.y * gridDim.x + blockIdx.x;
  const int nl = (lid0 & 7) * (total >> 3) + (lid0 >> 3);
  const int m0 = (nl / gridDim.x) * 128, n0 = (nl % gridDim.x) * 128;
  const int wrow = (w >> 1) * 64, wcol = (w & 1) * 64;
  const int lrow = l & 15, hi = l >> 4;
  // staging: issue j covers rows j*32..j*32+31 (4KB, linear dest = t*16B);
  // thread t -> row j*32 + (t>>3), chunk t&7; src chunk XOR'd by row&7.
  const int srow = t >> 3;
  const int scol = ((t & 7) ^ (srow & 7)) * 8;
  f32x4 acc[4][4] = {};

#define GSTAGE(buf, K0)                                                       \
  do {                                                                        \
    _Pragma("unroll") for (int j = 0; j < 4; ++j)                             \
        GLDS(A + (size_t)(m0 + j * 32 + srow) * K + (K0) + scol,              \
             &As[buf][0] + j * 2048 + t * 8);                                 \
    _Pragma("unroll") for (int j = 0; j < 4; ++j)                             \
        GLDS(B + (size_t)(n0 + j * 32 + srow) * K + (K0) + scol,              \
             &Bs[buf][0] + j * 2048 + t * 8);                                 \
  } while (0)

  const int nsteps = K >> 6;  // BK = 64
  GSTAGE(0, 0);
  __syncthreads();
#pragma unroll 1
  for (int kt = 0; kt < nsteps; ++kt) {
    if (kt < nsteps - 1) GSTAGE((kt + 1) & 1, (kt + 1) * 64);
    const unsigned short* Ac = &As[kt & 1][0];
    const unsigned short* Bc = &Bs[kt & 1][0];
    // fragment chunk for k-slice ks: chunk = hi + ks*4, swizzled by row&7
    bfrag af[4][2], bf[4][2];
#pragma unroll
    for (int mt = 0; mt < 4; ++mt) {
      const int row = wrow + mt * 16 + lrow;
#pragma unroll
      for (int ks = 0; ks < 2; ++ks)
        af[mt][ks] = *(const bfrag*)&Ac[row * 64 + (((hi + ks * 4) ^ (row & 7)) * 8)];
    }
#pragma unroll
    for (int nt = 0; nt < 4; ++nt) {
      const int row = wcol + nt * 16 + lrow;
#pragma unroll
      for (int ks = 0; ks < 2; ++ks)
        bf[nt][ks] = *(const bfrag*)&Bc[row * 64 + (((hi + ks * 4) ^ (row & 7)) * 8)];
    }
#pragma unroll
    for (int mt = 0; mt < 4; ++mt)
#pragma unroll
      for (int nt = 0; nt < 4; ++nt)
#pragma unroll
        for (int ks = 0; ks < 2; ++ks)
          acc[mt][nt] = __builtin_amdgcn_mfma_f32_16x16x32_bf16(af[mt][ks], bf[nt][ks],
                                                                acc[mt][nt], 0, 0, 0);
    __syncthreads();
  }
#undef GSTAGE
#pragma unroll
  for (int nt = 0; nt < 4; ++nt) {
    int gn = n0 + wcol + nt * 16 + lrow;
    float bv = bias[gn];
    if constexpr (EPI == 0) {
      int sel = gn >> 10;
      int e = gn & 1023;
      int h = e >> 6, d = e & 63;
#pragma unroll
      for (int mt = 0; mt < 4; ++mt) {
#pragma unroll
        for (int r = 0; r < 4; ++r) {
          int gm = m0 + wrow + mt * 16 + hi * 4 + r;
          int b = gm >> 11, s = gm & 2047;
          float fv = acc[mt][nt][r] + bv;
          if (sel == 0)
            q_out[((size_t)(b * NH + h) * SEQ + s) * HD + d] = f2bf(fv * QSCALE);
          else if (sel == 1)
            k_out[((size_t)(b * NH + h) * SEQ + s) * HD + d] = f2bf(fv);
          else
            v_out[((size_t)(b * NH + h) * HD + d) * SEQ + s] = f2bf(fv);
        }
      }
    } else {
#pragma unroll
      for (int mt = 0; mt < 4; ++mt) {
#pragma unroll
        for (int r = 0; r < 4; ++r) {
          int gm = m0 + wrow + mt * 16 + hi * 4 + r;
          f_out[(size_t)gm * N + gn] = acc[mt][nt][r] + bv;
        }
      }
    }
  }
}

// ---------------- flash attention (r8 structure — best known, 48us) ----------------
// Fixed-shift softmax, KV tile 128, ring-2 LDS, wave-staggered subtiles + 2-deep pipe.
__global__ __launch_bounds__(256, 2)
void attn_kernel(const unsigned short* __restrict__ Q,
                 const unsigned short* __restrict__ Km,
                 const unsigned short* __restrict__ Vt,
                 unsigned short* __restrict__ Ctx) {
  __shared__ __align__(16) unsigned short Ks[2][128 * 64];
  __shared__ __align__(16) unsigned short Vs[2][64 * 128];
  const int t = threadIdx.x;
  const int l = t & 63, w = t >> 6;
  const int q31 = l & 31, h = l >> 5;
  const int lid = blockIdx.y * gridDim.x + blockIdx.x;
  const int bh = (lid & 7) * 4 + ((lid >> 3) >> 4);
  const int q0 = ((lid >> 3) & 15) * 128 + w * 32;
  const unsigned short* qb = Q + (size_t)bh * SEQ * HD;
  const unsigned short* kb = Km + (size_t)bh * SEQ * HD;
  const unsigned short* vb = Vt + (size_t)bh * HD * SEQ;

  bfrag qf[4];
#pragma unroll
  for (int c = 0; c < 4; ++c)
    qf[c] = *(const bfrag*)&qb[(size_t)(q0 + q31) * HD + c * 16 + h * 8];

  f32x16 acc0 = {}, acc1 = {};
  float llocal = 0.f;

  const int skr = t >> 3;
  const int sks = ((t & 7) ^ (skr & 7)) * 8;
  const int svr = t >> 4;
  const int svs = ((t & 15) ^ svr) * 8;

#define STAGE(buf, T)                                                          \
  do {                                                                         \
    const int kv0_ = (T) * 128;                                                \
    _Pragma("unroll") for (int j = 0; j < 4; ++j)                              \
        GLDS(kb + (size_t)(kv0_ + 32 * j + skr) * HD + sks,                    \
             &Ks[buf][0] + j * 2048 + t * 8);                                  \
    _Pragma("unroll") for (int j = 0; j < 4; ++j)                              \
        GLDS(vb + (size_t)(16 * j + svr) * SEQ + kv0_ + svs,                   \
             &Vs[buf][0] + j * 2048 + t * 8);                                  \
  } while (0)

  STAGE(0, 0);
  __syncthreads();

  const int sw7 = q31 & 7, sw15 = q31 & 15;
  const int st0 = w & 3;

#define LOADK(kfv, stx)                                                        \
  _Pragma("unroll") for (int c = 0; c < 4; ++c)                                \
      kfv[c] = *(const bfrag*)&Kc[((stx) * 32 + q31) * 64 +                    \
                                  (((2 * c + h) ^ sw7) * 8)]

#define QK4(dst, kfv)                                                          \
  do {                                                                         \
    dst = (f32x16){};                                                          \
    __builtin_amdgcn_s_setprio(1);                                             \
    _Pragma("unroll") for (int c = 0; c < 4; ++c)                              \
        dst = __builtin_amdgcn_mfma_f32_32x32x16_bf16(kfv[c], qf[c], dst, 0, 0, 0); \
    __builtin_amdgcn_s_setprio(0);                                             \
  } while (0)

#define SOFTPV(stx, SV)                                                        \
  do {                                                                         \
    _Pragma("unroll") for (int r = 0; r < 16; ++r)                             \
        SV[r] = __builtin_amdgcn_exp2f(SV[r]);                                 \
    llocal += rsum16(SV);                                                      \
    _Pragma("unroll") for (int u = 0; u < 2; ++u) {                            \
      const int win = (stx) * 2 + u;                                           \
      const int bse = u * 8;                                                   \
      unsigned pk0 = cvt_pk_bf16(SV[bse + 0], SV[bse + 1]);                    \
      unsigned pk1 = cvt_pk_bf16(SV[bse + 2], SV[bse + 3]);                    \
      unsigned pk2 = cvt_pk_bf16(SV[bse + 4], SV[bse + 5]);                    \
      unsigned pk3 = cvt_pk_bf16(SV[bse + 6], SV[bse + 7]);                    \
      auto w02 = __builtin_amdgcn_permlane32_swap(pk0, pk2, false, false);     \
      auto w13 = __builtin_amdgcn_permlane32_swap(pk1, pk3, false, false);     \
      u32x4 bw = {(unsigned)w02[0], (unsigned)w13[0], (unsigned)w02[1],        \
                  (unsigned)w13[1]};                                           \
      bfrag pb = __builtin_bit_cast(bfrag, bw);                                \
      const int vchunk = ((win * 2 + h) ^ sw15) * 8;                           \
      bfrag vf0 = *(const bfrag*)&Vc[q31 * 128 + vchunk];                      \
      bfrag vf1 = *(const bfrag*)&Vc[(32 + q31) * 128 + vchunk];               \
      __builtin_amdgcn_s_setprio(1);                                           \
      acc0 = __builtin_amdgcn_mfma_f32_32x32x16_bf16(vf0, pb, acc0, 0, 0, 0);  \
      acc1 = __builtin_amdgcn_mfma_f32_32x32x16_bf16(vf1, pb, acc1, 0, 0, 0);  \
      __builtin_amdgcn_s_setprio(0);                                           \
    }                                                                          \
  } while (0)

#pragma unroll 1
  for (int t2 = 0; t2 < 16; ++t2) {
    const unsigned short* Kc = &Ks[t2 & 1][0];
    const unsigned short* Vc = &Vs[t2 & 1][0];
    bfrag kfa[4], kfb[4];
    f32x16 scur, snxt;
    LOADK(kfa, st0);
    QK4(scur, kfa);
    if (t2 < 15) STAGE((t2 + 1) & 1, t2 + 1);
#pragma unroll
    for (int j = 0; j < 4; ++j) {
      if (j < 3) {
        const int stn = (st0 + j + 1) & 3;
        LOADK(kfb, stn);
        QK4(snxt, kfb);
      }
      const int stc = (st0 + j) & 3;
      SOFTPV(stc, scur);
      scur = snxt;
    }
    __syncthreads();
  }
#undef STAGE
#undef LOADK
#undef QK4
#undef SOFTPV

  const int b = bh >> 4, head = bh & 15;
  float lsum = llocal + __shfl_xor(llocal, 32);
  const float inv = __builtin_amdgcn_rcpf(lsum);
  unsigned short* cp = Ctx + ((size_t)(b * SEQ + (q0 + q31)) * NH + head) * HD;
#pragma unroll
  for (int dt = 0; dt < 2; ++dt) {
    const f32x16 av = dt ? acc1 : acc0;
#pragma unroll
    for (int rq = 0; rq < 4; ++rq) {
      u16x4 o;
#pragma unroll
      for (int rr = 0; rr < 4; ++rr) o[rr] = f2bf(av[rq * 4 + rr] * inv);
      *(u16x4*)&cp[dt * 32 + rq * 8 + h * 4] = o;
    }
  }
}

extern "C" void kernel_launch(void* const* d_in, const int* in_sizes, int n_in,
                              void* d_out, int out_size, void* d_ws, size_t ws_size,
                              hipStream_t stream) {
  const float* x = (const float*)d_in[0];
  const float* wqkv = (const float*)d_in[1];
  const float* bqkv = (const float*)d_in[2];
  const float* wout = (const float*)d_in[3];
  const float* bout = (const float*)d_in[4];
  float* out = (float*)d_out;

  unsigned short* xb = (unsigned short*)d_ws;
  unsigned short* wqkvb = xb + (size_t)MTOT * DMODEL;
  unsigned short* woutb = wqkvb + (size_t)3 * DMODEL * DMODEL;
  unsigned short* qb = woutb + (size_t)DMODEL * DMODEL;
  unsigned short* kb = qb + (size_t)32 * SEQ * HD;
  unsigned short* vtb = kb + (size_t)32 * SEQ * HD;
  unsigned short* ctxb = vtb + (size_t)32 * SEQ * HD;

  cvt_all_kernel<<<(XG + WQG + WOG + 255) / 256, 256, 0, stream>>>(x, wqkv, wout, xb);
  gemm_bt_kernel<0><<<dim3(3 * DMODEL / 128, MTOT / 128), 256, 0, stream>>>(
      xb, wqkvb, bqkv, qb, kb, vtb, nullptr, MTOT, 3 * DMODEL, DMODEL);
  attn_kernel<<<dim3(SEQ / 128, 32), 256, 0, stream>>>(qb, kb, vtb, ctxb);
  gemm_bt_kernel<1><<<dim3(DMODEL / 128, MTOT / 128), 256, 0, stream>>>(
      ctxb, woutb, bout, nullptr, nullptr, nullptr, out, MTOT, DMODEL, DMODEL);
}

// Round 16
// 116.187 us; speedup vs baseline: 1.0972x; 1.0972x over previous
//
#include <hip/hip_runtime.h>
#include <hip/hip_bf16.h>

typedef __attribute__((ext_vector_type(8))) __bf16 bfrag;
typedef __attribute__((ext_vector_type(4))) float f32x4;
typedef __attribute__((ext_vector_type(16))) float f32x16;
typedef __attribute__((ext_vector_type(8))) unsigned short u16x8;
typedef __attribute__((ext_vector_type(4))) unsigned short u16x4;
typedef __attribute__((ext_vector_type(4))) unsigned int u32x4;

#define SEQ 2048
#define NH 16
#define HD 64
#define DMODEL 1024
#define MTOT 4096
// 1/sqrt(64) * log2(e): folded into Q so softmax uses exp2 directly
#define QSCALE 0.18033688011112042f

static __device__ __forceinline__ unsigned short f2bf(float f) {
  unsigned int u = __builtin_bit_cast(unsigned int, f);
  u += 0x7FFFu + ((u >> 16) & 1u);
  return (unsigned short)(u >> 16);
}

static __device__ __forceinline__ unsigned cvt_pk_bf16(float lo, float hi) {
  unsigned r;
  asm("v_cvt_pk_bf16_f32 %0, %1, %2" : "=v"(r) : "v"(lo), "v"(hi));
  return r;
}

static __device__ __forceinline__ float rsum16(const f32x16 v) {
  float a0 = v[0] + v[1], a1 = v[2] + v[3], a2 = v[4] + v[5], a3 = v[6] + v[7];
  float a4 = v[8] + v[9], a5 = v[10] + v[11], a6 = v[12] + v[13], a7 = v[14] + v[15];
  float b0 = a0 + a1, b1 = a2 + a3, b2 = a4 + a5, b3 = a6 + a7;
  return (b0 + b1) + (b2 + b3);
}

// ---------------- f32 -> bf16 convert: all three tensors in ONE launch -------------
#define XG 524288   // 4096*1024/8
#define WQG 393216  // 3*1024*1024/8
#define WOG 131072  // 1024*1024/8
__global__ __launch_bounds__(256) void cvt_all_kernel(const float* __restrict__ x,
                                                      const float* __restrict__ wq,
                                                      const float* __restrict__ wo,
                                                      unsigned short* __restrict__ out) {
  int i = blockIdx.x * 256 + threadIdx.x;
  if (i >= XG + WQG + WOG) return;
  const float4* p;
  if (i < XG) p = reinterpret_cast<const float4*>(x) + (size_t)i * 2;
  else if (i < XG + WQG) p = reinterpret_cast<const float4*>(wq) + (size_t)(i - XG) * 2;
  else p = reinterpret_cast<const float4*>(wo) + (size_t)(i - XG - WQG) * 2;
  float4 a = p[0], b = p[1];
  u16x8 o;
  o[0] = f2bf(a.x); o[1] = f2bf(a.y); o[2] = f2bf(a.z); o[3] = f2bf(a.w);
  o[4] = f2bf(b.x); o[5] = f2bf(b.y); o[6] = f2bf(b.z); o[7] = f2bf(b.w);
  *(reinterpret_cast<u16x8*>(out) + i) = o;
}

#define GLDS(gp, lp)                                                       \
  __builtin_amdgcn_global_load_lds(                                        \
      (const __attribute__((address_space(1))) void*)(gp),                 \
      (__attribute__((address_space(3))) void*)(lp), 16, 0, 0)

// ---------------- QKV GEMM, 128x128, BK=32, ring-3 + counted vmcnt (r14 proven) -----
__global__ __launch_bounds__(256) void gemm_qkv_kernel(
    const unsigned short* __restrict__ A, const unsigned short* __restrict__ B,
    const float* __restrict__ bias, unsigned short* __restrict__ q_out,
    unsigned short* __restrict__ k_out, unsigned short* __restrict__ v_out,
    int M, int N, int K) {
  __shared__ __align__(16) unsigned short As[3][4096];
  __shared__ __align__(16) unsigned short Bs[3][4096];
  const int t = threadIdx.x;
  const int l = t & 63, w = t >> 6;
  const int total = gridDim.x * gridDim.y;
  const int lid0 = blockIdx.y * gridDim.x + blockIdx.x;
  const int nl = (lid0 & 7) * (total >> 3) + (lid0 >> 3);
  const int m0 = (nl / gridDim.x) * 128, n0 = (nl % gridDim.x) * 128;
  const int wrow = (w >> 1) * 64, wcol = (w & 1) * 64;
  const int lrow = l & 15, lk = (l >> 4) * 8;
  const int srow = t >> 2;
  const int scol = ((t & 3) ^ (srow & 3)) * 8;
  f32x4 acc[4][4] = {};

#define GSTAGE(buf, K0)                                                     \
  do {                                                                      \
    GLDS(A + (size_t)(m0 + srow) * K + (K0) + scol, &As[buf][0] + t * 8);   \
    GLDS(A + (size_t)(m0 + srow + 64) * K + (K0) + scol,                    \
         &As[buf][0] + 2048 + t * 8);                                       \
    GLDS(B + (size_t)(n0 + srow) * K + (K0) + scol, &Bs[buf][0] + t * 8);   \
    GLDS(B + (size_t)(n0 + srow + 64) * K + (K0) + scol,                    \
         &Bs[buf][0] + 2048 + t * 8);                                       \
  } while (0)

  const int nsteps = K >> 5;
  GSTAGE(0, 0);
  GSTAGE(1, 32);
#pragma unroll 1
  for (int ks = 0; ks < nsteps; ++ks) {
    if (ks < nsteps - 1)
      asm volatile("s_waitcnt vmcnt(4)" ::: "memory");
    else
      asm volatile("s_waitcnt vmcnt(0)" ::: "memory");
    __builtin_amdgcn_s_barrier();
    __builtin_amdgcn_sched_barrier(0);
    if (ks + 2 < nsteps) GSTAGE((ks + 2) % 3, (ks + 2) * 32);
    const unsigned short* Ac = &As[ks % 3][0];
    const unsigned short* Bc = &Bs[ks % 3][0];
    bfrag af[4], bf[4];
#pragma unroll
    for (int mt = 0; mt < 4; ++mt) {
      int row = wrow + mt * 16 + lrow;
      af[mt] = *(const bfrag*)&Ac[row * 32 + (lk ^ ((row & 3) << 3))];
    }
#pragma unroll
    for (int nt = 0; nt < 4; ++nt) {
      int row = wcol + nt * 16 + lrow;
      bf[nt] = *(const bfrag*)&Bc[row * 32 + (lk ^ ((row & 3) << 3))];
    }
#pragma unroll
    for (int mt = 0; mt < 4; ++mt)
#pragma unroll
      for (int nt = 0; nt < 4; ++nt)
        acc[mt][nt] =
            __builtin_amdgcn_mfma_f32_16x16x32_bf16(af[mt], bf[nt], acc[mt][nt], 0, 0, 0);
  }
#undef GSTAGE
#pragma unroll
  for (int nt = 0; nt < 4; ++nt) {
    int gn = n0 + wcol + nt * 16 + lrow;
    float bv = bias[gn];
    int sel = gn >> 10;
    int e = gn & 1023;
    int h = e >> 6, d = e & 63;
#pragma unroll
    for (int mt = 0; mt < 4; ++mt) {
#pragma unroll
      for (int r = 0; r < 4; ++r) {
        int gm = m0 + wrow + mt * 16 + (l >> 4) * 4 + r;
        int b = gm >> 11, s = gm & 2047;
        float fv = acc[mt][nt][r] + bv;
        if (sel == 0)
          q_out[((size_t)(b * NH + h) * SEQ + s) * HD + d] = f2bf(fv * QSCALE);
        else if (sel == 1)
          k_out[((size_t)(b * NH + h) * SEQ + s) * HD + d] = f2bf(fv);
        else
          v_out[((size_t)(b * NH + h) * HD + d) * SEQ + s] = f2bf(fv);
      }
    }
  }
}

// ---------------- out-proj GEMM, 64x128 tile (r16): 512 blocks -> 2 blocks/CU -------
// r14's out-proj grid was 256 blocks = 1 block/CU = 1 wave/SIMD — half the residency
// of every other kernel. M-tile 64 doubles the grid; same ring-3/BK=32/counted-vmcnt
// structure, 3 loads/stage (A=1 issue, B=2), wait vmcnt(3). acc[2][4] = 32 VGPR.
__global__ __launch_bounds__(256) void gemm_out_kernel(
    const unsigned short* __restrict__ A, const unsigned short* __restrict__ B,
    const float* __restrict__ bias, float* __restrict__ f_out, int M, int N, int K) {
  __shared__ __align__(16) unsigned short As[3][2048];  // [64][32]
  __shared__ __align__(16) unsigned short Bs[3][4096];  // [128][32]
  const int t = threadIdx.x;
  const int l = t & 63, w = t >> 6;
  const int total = gridDim.x * gridDim.y;
  const int lid0 = blockIdx.y * gridDim.x + blockIdx.x;
  const int nl = (lid0 & 7) * (total >> 3) + (lid0 >> 3);
  const int m0 = (nl / gridDim.x) * 64, n0 = (nl % gridDim.x) * 128;
  const int wrow = (w >> 1) * 32, wcol = (w & 1) * 64;
  const int lrow = l & 15, lk = (l >> 4) * 8;
  const int srow = t >> 2;
  const int scol = ((t & 3) ^ (srow & 3)) * 8;
  f32x4 acc[2][4] = {};

#define GSTAGE(buf, K0)                                                     \
  do {                                                                      \
    GLDS(A + (size_t)(m0 + srow) * K + (K0) + scol, &As[buf][0] + t * 8);   \
    GLDS(B + (size_t)(n0 + srow) * K + (K0) + scol, &Bs[buf][0] + t * 8);   \
    GLDS(B + (size_t)(n0 + srow + 64) * K + (K0) + scol,                    \
         &Bs[buf][0] + 2048 + t * 8);                                       \
  } while (0)

  const int nsteps = K >> 5;
  GSTAGE(0, 0);
  GSTAGE(1, 32);
#pragma unroll 1
  for (int ks = 0; ks < nsteps; ++ks) {
    if (ks < nsteps - 1)
      asm volatile("s_waitcnt vmcnt(3)" ::: "memory");
    else
      asm volatile("s_waitcnt vmcnt(0)" ::: "memory");
    __builtin_amdgcn_s_barrier();
    __builtin_amdgcn_sched_barrier(0);
    if (ks + 2 < nsteps) GSTAGE((ks + 2) % 3, (ks + 2) * 32);
    const unsigned short* Ac = &As[ks % 3][0];
    const unsigned short* Bc = &Bs[ks % 3][0];
    bfrag af[2], bf[4];
#pragma unroll
    for (int mt = 0; mt < 2; ++mt) {
      int row = wrow + mt * 16 + lrow;
      af[mt] = *(const bfrag*)&Ac[row * 32 + (lk ^ ((row & 3) << 3))];
    }
#pragma unroll
    for (int nt = 0; nt < 4; ++nt) {
      int row = wcol + nt * 16 + lrow;
      bf[nt] = *(const bfrag*)&Bc[row * 32 + (lk ^ ((row & 3) << 3))];
    }
#pragma unroll
    for (int mt = 0; mt < 2; ++mt)
#pragma unroll
      for (int nt = 0; nt < 4; ++nt)
        acc[mt][nt] =
            __builtin_amdgcn_mfma_f32_16x16x32_bf16(af[mt], bf[nt], acc[mt][nt], 0, 0, 0);
  }
#undef GSTAGE
#pragma unroll
  for (int nt = 0; nt < 4; ++nt) {
    int gn = n0 + wcol + nt * 16 + lrow;
    float bv = bias[gn];
#pragma unroll
    for (int mt = 0; mt < 2; ++mt) {
#pragma unroll
      for (int r = 0; r < 4; ++r) {
        int gm = m0 + wrow + mt * 16 + (l >> 4) * 4 + r;
        f_out[(size_t)gm * N + gn] = acc[mt][nt][r] + bv;
      }
    }
  }
}

// ---------------- flash attention (r8 structure — best known, 48us) ----------------
__global__ __launch_bounds__(256, 2)
void attn_kernel(const unsigned short* __restrict__ Q,
                 const unsigned short* __restrict__ Km,
                 const unsigned short* __restrict__ Vt,
                 unsigned short* __restrict__ Ctx) {
  __shared__ __align__(16) unsigned short Ks[2][128 * 64];
  __shared__ __align__(16) unsigned short Vs[2][64 * 128];
  const int t = threadIdx.x;
  const int l = t & 63, w = t >> 6;
  const int q31 = l & 31, h = l >> 5;
  const int lid = blockIdx.y * gridDim.x + blockIdx.x;
  const int bh = (lid & 7) * 4 + ((lid >> 3) >> 4);
  const int q0 = ((lid >> 3) & 15) * 128 + w * 32;
  const unsigned short* qb = Q + (size_t)bh * SEQ * HD;
  const unsigned short* kb = Km + (size_t)bh * SEQ * HD;
  const unsigned short* vb = Vt + (size_t)bh * HD * SEQ;

  bfrag qf[4];
#pragma unroll
  for (int c = 0; c < 4; ++c)
    qf[c] = *(const bfrag*)&qb[(size_t)(q0 + q31) * HD + c * 16 + h * 8];

  f32x16 acc0 = {}, acc1 = {};
  float llocal = 0.f;

  const int skr = t >> 3;
  const int sks = ((t & 7) ^ (skr & 7)) * 8;
  const int svr = t >> 4;
  const int svs = ((t & 15) ^ svr) * 8;

#define STAGE(buf, T)                                                          \
  do {                                                                         \
    const int kv0_ = (T) * 128;                                                \
    _Pragma("unroll") for (int j = 0; j < 4; ++j)                              \
        GLDS(kb + (size_t)(kv0_ + 32 * j + skr) * HD + sks,                    \
             &Ks[buf][0] + j * 2048 + t * 8);                                  \
    _Pragma("unroll") for (int j = 0; j < 4; ++j)                              \
        GLDS(vb + (size_t)(16 * j + svr) * SEQ + kv0_ + svs,                   \
             &Vs[buf][0] + j * 2048 + t * 8);                                  \
  } while (0)

  STAGE(0, 0);
  __syncthreads();

  const int sw7 = q31 & 7, sw15 = q31 & 15;
  const int st0 = w & 3;

#define LOADK(kfv, stx)                                                        \
  _Pragma("unroll") for (int c = 0; c < 4; ++c)                                \
      kfv[c] = *(const bfrag*)&Kc[((stx) * 32 + q31) * 64 +                    \
                                  (((2 * c + h) ^ sw7) * 8)]

#define QK4(dst, kfv)                                                          \
  do {                                                                         \
    dst = (f32x16){};                                                          \
    __builtin_amdgcn_s_setprio(1);                                             \
    _Pragma("unroll") for (int c = 0; c < 4; ++c)                              \
        dst = __builtin_amdgcn_mfma_f32_32x32x16_bf16(kfv[c], qf[c], dst, 0, 0, 0); \
    __builtin_amdgcn_s_setprio(0);                                             \
  } while (0)

#define SOFTPV(stx, SV)                                                        \
  do {                                                                         \
    _Pragma("unroll") for (int r = 0; r < 16; ++r)                             \
        SV[r] = __builtin_amdgcn_exp2f(SV[r]);                                 \
    llocal += rsum16(SV);                                                      \
    _Pragma("unroll") for (int u = 0; u < 2; ++u) {                            \
      const int win = (stx) * 2 + u;                                           \
      const int bse = u * 8;                                                   \
      unsigned pk0 = cvt_pk_bf16(SV[bse + 0], SV[bse + 1]);                    \
      unsigned pk1 = cvt_pk_bf16(SV[bse + 2], SV[bse + 3]);                    \
      unsigned pk2 = cvt_pk_bf16(SV[bse + 4], SV[bse + 5]);                    \
      unsigned pk3 = cvt_pk_bf16(SV[bse + 6], SV[bse + 7]);                    \
      auto w02 = __builtin_amdgcn_permlane32_swap(pk0, pk2, false, false);     \
      auto w13 = __builtin_amdgcn_permlane32_swap(pk1, pk3, false, false);     \
      u32x4 bw = {(unsigned)w02[0], (unsigned)w13[0], (unsigned)w02[1],        \
                  (unsigned)w13[1]};                                           \
      bfrag pb = __builtin_bit_cast(bfrag, bw);                                \
      const int vchunk = ((win * 2 + h) ^ sw15) * 8;                           \
      bfrag vf0 = *(const bfrag*)&Vc[q31 * 128 + vchunk];                      \
      bfrag vf1 = *(const bfrag*)&Vc[(32 + q31) * 128 + vchunk];               \
      __builtin_amdgcn_s_setprio(1);                                           \
      acc0 = __builtin_amdgcn_mfma_f32_32x32x16_bf16(vf0, pb, acc0, 0, 0, 0);  \
      acc1 = __builtin_amdgcn_mfma_f32_32x32x16_bf16(vf1, pb, acc1, 0, 0, 0);  \
      __builtin_amdgcn_s_setprio(0);                                           \
    }                                                                          \
  } while (0)

#pragma unroll 1
  for (int t2 = 0; t2 < 16; ++t2) {
    const unsigned short* Kc = &Ks[t2 & 1][0];
    const unsigned short* Vc = &Vs[t2 & 1][0];
    bfrag kfa[4], kfb[4];
    f32x16 scur, snxt;
    LOADK(kfa, st0);
    QK4(scur, kfa);
    if (t2 < 15) STAGE((t2 + 1) & 1, t2 + 1);
#pragma unroll
    for (int j = 0; j < 4; ++j) {
      if (j < 3) {
        const int stn = (st0 + j + 1) & 3;
        LOADK(kfb, stn);
        QK4(snxt, kfb);
      }
      const int stc = (st0 + j) & 3;
      SOFTPV(stc, scur);
      scur = snxt;
    }
    __syncthreads();
  }
#undef STAGE
#undef LOADK
#undef QK4
#undef SOFTPV

  const int b = bh >> 4, head = bh & 15;
  float lsum = llocal + __shfl_xor(llocal, 32);
  const float inv = __builtin_amdgcn_rcpf(lsum);
  unsigned short* cp = Ctx + ((size_t)(b * SEQ + (q0 + q31)) * NH + head) * HD;
#pragma unroll
  for (int dt = 0; dt < 2; ++dt) {
    const f32x16 av = dt ? acc1 : acc0;
#pragma unroll
    for (int rq = 0; rq < 4; ++rq) {
      u16x4 o;
#pragma unroll
      for (int rr = 0; rr < 4; ++rr) o[rr] = f2bf(av[rq * 4 + rr] * inv);
      *(u16x4*)&cp[dt * 32 + rq * 8 + h * 4] = o;
    }
  }
}

extern "C" void kernel_launch(void* const* d_in, const int* in_sizes, int n_in,
                              void* d_out, int out_size, void* d_ws, size_t ws_size,
                              hipStream_t stream) {
  const float* x = (const float*)d_in[0];
  const float* wqkv = (const float*)d_in[1];
  const float* bqkv = (const float*)d_in[2];
  const float* wout = (const float*)d_in[3];
  const float* bout = (const float*)d_in[4];
  float* out = (float*)d_out;

  unsigned short* xb = (unsigned short*)d_ws;
  unsigned short* wqkvb = xb + (size_t)MTOT * DMODEL;
  unsigned short* woutb = wqkvb + (size_t)3 * DMODEL * DMODEL;
  unsigned short* qb = woutb + (size_t)DMODEL * DMODEL;
  unsigned short* kb = qb + (size_t)32 * SEQ * HD;
  unsigned short* vtb = kb + (size_t)32 * SEQ * HD;
  unsigned short* ctxb = vtb + (size_t)32 * SEQ * HD;

  cvt_all_kernel<<<(XG + WQG + WOG + 255) / 256, 256, 0, stream>>>(x, wqkv, wout, xb);
  gemm_qkv_kernel<<<dim3(3 * DMODEL / 128, MTOT / 128), 256, 0, stream>>>(
      xb, wqkvb, bqkv, qb, kb, vtb, MTOT, 3 * DMODEL, DMODEL);
  attn_kernel<<<dim3(SEQ / 128, 32), 256, 0, stream>>>(qb, kb, vtb, ctxb);
  gemm_out_kernel<<<dim3(DMODEL / 128, MTOT / 64), 256, 0, stream>>>(
      ctxb, woutb, bout, out, MTOT, DMODEL, DMODEL);
}